// Round 5
// baseline (1514.295 us; speedup 1.0000x reference)
//
#include <hip/hip_runtime.h>

typedef _Float16 h2 __attribute__((ext_vector_type(2)));
typedef _Float16 h4 __attribute__((ext_vector_type(4)));
typedef _Float16 h8 __attribute__((ext_vector_type(8)));
typedef float f4v __attribute__((ext_vector_type(4)));

#define U_DIM 256
#define M_DIM 256
#define T_DIM 512

__device__ __forceinline__ float fast_sigmoid(float z) {
  return __builtin_amdgcn_rcpf(1.f + __expf(-z));
}
__device__ __forceinline__ float fast_tanh(float z) {
  return fmaf(2.f, __builtin_amdgcn_rcpf(1.f + __expf(-2.f * z)), -1.f);
}

// ---------------- prep: x fp32 -> fp16 (same [M][T][256] layout) ------------
__global__ void conv_x(const float* __restrict__ x, h8* __restrict__ x16, int n8) {
  int i = blockIdx.x * 256 + threadIdx.x;
  if (i >= n8) return;
  const float4* p = (const float4*)(x + (size_t)i * 8);
  float4 v0 = p[0], v1 = p[1];
  h8 o = {(_Float16)v0.x, (_Float16)v0.y, (_Float16)v0.z, (_Float16)v0.w,
          (_Float16)v1.x, (_Float16)v1.y, (_Float16)v1.z, (_Float16)v1.w};
  x16[i] = o;
}

// ------- prep: x-projection weights -> fp16 TRANSPOSED [mtx][n][k] ----------
__global__ void prep_xw(const float* __restrict__ wux, const float* __restrict__ wrx,
                        const float* __restrict__ wcx, h8* __restrict__ wt16) {
  int idx = blockIdx.x * 256 + threadIdx.x;   // 0..24575
  int mtx = idx >> 13;
  int rem = idx & 8191;
  int n = rem >> 5;
  int kv = rem & 31;
  const float* W = (mtx == 0) ? wux : ((mtx == 1) ? wrx : wcx);
  h8 o;
#pragma unroll
  for (int e = 0; e < 8; ++e) o[e] = (_Float16)W[(size_t)(kv * 8 + e) * U_DIM + n];
  wt16[idx] = o;
}

// ------- prep: recurrent weights as MFMA A-fragments of W^T -----------------
// wa[((mtx*16 + ut)*8 + kk)*64 + lane], element j = W[kk*32 + (lane>>4)*8 + j][ut*16 + (lane&15)]
// (A-frag mapping A[m=lane&15][k=quad*8+j], m = output unit, verified r4)
__global__ void prep_wa(const float* __restrict__ wuc, const float* __restrict__ wrc,
                        const float* __restrict__ wcc, h8* __restrict__ wa) {
  int idx = blockIdx.x * 256 + threadIdx.x;   // 0..24575 (3*16*8*64)
  int mtx = idx / 8192;
  int rem = idx & 8191;
  int ut = rem >> 9;
  int kk = (rem >> 6) & 7;
  int lane = rem & 63;
  const float* W = (mtx == 0) ? wuc : ((mtx == 1) ? wrc : wcc);
  int u = ut * 16 + (lane & 15);
  int k0 = kk * 32 + (lane >> 4) * 8;
  h8 o;
#pragma unroll
  for (int e = 0; e < 8; ++e) o[e] = (_Float16)W[(size_t)(k0 + e) * U_DIM + u];
  wa[idx] = o;
}

// ---------------- xproj via fp16 MFMA, fp16 OUTPUT --------------------------
__global__ __launch_bounds__(256, 2)
void xproj_mfma(const h8* __restrict__ x16, const h8* __restrict__ wt16,
                const float* __restrict__ Bu, const float* __restrict__ Br,
                const float* __restrict__ Bc,
                _Float16* __restrict__ XU, _Float16* __restrict__ XR,
                _Float16* __restrict__ XC, int t0, int len) {
  const int mtx = blockIdx.z;
  const float* Bv = (mtx == 0) ? Bu : ((mtx == 1) ? Br : Bc);
  _Float16* O = (mtx == 0) ? XU : ((mtx == 1) ? XR : XC);
  const h8* W = wt16 + (size_t)mtx * 256 * 32;

  __shared__ _Float16 a_sh[128][40];
  __shared__ _Float16 b_sh[128][40];

  const int tid = threadIdx.x;
  const int r0 = blockIdx.x * 128;
  const int c0 = blockIdx.y * 128;

  const int srow = tid >> 1;
  const int spart = tid & 1;
  const int r = r0 + srow;
  const int mm = r / len;
  const int tc = r - mm * len;
  const h8* arow = x16 + ((size_t)mm * T_DIM + (size_t)(t0 + tc)) * 32;
  const h8* brow = W + (size_t)(c0 + srow) * 32;

  const int lane = tid & 63;
  const int w = tid >> 6;
  const int quad = lane >> 4;
  const int mrow = lane & 15;

  f4v acc[2][8];
#pragma unroll
  for (int fr = 0; fr < 2; ++fr)
#pragma unroll
    for (int fc = 0; fc < 8; ++fc) acc[fr][fc] = f4v{0.f, 0.f, 0.f, 0.f};

  for (int k8 = 0; k8 < 32; k8 += 4) {
    h8 a0 = arow[k8 + 2 * spart];
    h8 a1 = arow[k8 + 2 * spart + 1];
    h8 b0 = brow[k8 + 2 * spart];
    h8 b1 = brow[k8 + 2 * spart + 1];
    __syncthreads();
    *(h8*)&a_sh[srow][spart * 16]     = a0;
    *(h8*)&a_sh[srow][spart * 16 + 8] = a1;
    *(h8*)&b_sh[srow][spart * 16]     = b0;
    *(h8*)&b_sh[srow][spart * 16 + 8] = b1;
    __syncthreads();
    h8 af0 = *(const h8*)&a_sh[32 * w + mrow][quad * 8];
    h8 af1 = *(const h8*)&a_sh[32 * w + 16 + mrow][quad * 8];
#pragma unroll
    for (int fc = 0; fc < 8; ++fc) {
      h8 bf = *(const h8*)&b_sh[fc * 16 + mrow][quad * 8];
      acc[0][fc] = __builtin_amdgcn_mfma_f32_16x16x32_f16(af0, bf, acc[0][fc], 0, 0, 0);
      acc[1][fc] = __builtin_amdgcn_mfma_f32_16x16x32_f16(af1, bf, acc[1][fc], 0, 0, 0);
    }
  }

#pragma unroll
  for (int fc = 0; fc < 8; ++fc) {
    int col = c0 + fc * 16 + mrow;
    float bb = Bv[col];
#pragma unroll
    for (int fr = 0; fr < 2; ++fr)
#pragma unroll
      for (int reg = 0; reg < 4; ++reg) {
        int rr = r0 + 32 * w + fr * 16 + quad * 4 + reg;
        O[(size_t)rr * U_DIM + col] = (_Float16)(acc[fr][fc][reg] + bb);
      }
  }
}

// ---------------- recurrence via MFMA: 16 blocks x 16 batch rows ------------
// Transposed: D[u][n] = W^T[u,:] @ c^T[:,n].  A = W^T static in 48 named h8
// (register-resident); B = c^T from LDS (1 b128 feeds 4 MFMAs -> DS-instr
// count 2x down vs scalar-dot r4 kernel, each instr moves 1KB unique data).
// State cv kept fp32 in registers in C/D layout; only matmul inputs are fp16.
__global__ __launch_bounds__(512, 2)
void gru_mfma(const _Float16* __restrict__ XU, const _Float16* __restrict__ XR,
              const _Float16* __restrict__ XC, const h8* __restrict__ wa,
              const float* __restrict__ c_in, float* __restrict__ c_out, int len) {
  const int m0 = blockIdx.x * 16;
  const int tid = threadIdx.x;
  const int lane = tid & 63;
  const int w = tid >> 6;        // wave 0..7, owns units [32w, 32w+32)
  const int quad = lane >> 4;
  const int n = lane & 15;       // batch row within block

  // c_t / grc_t layout: halves[(k8*16 + n)*8 + j] = val[row n][k = k8*8+j]
  __shared__ h8 ct[512];   // 8 KB
  __shared__ h8 gt[512];

#define DECLW(NM, MI, TI) \
  h8 NM##_0, NM##_1, NM##_2, NM##_3, NM##_4, NM##_5, NM##_6, NM##_7; \
  { const h8* p = wa + (size_t)((((MI)*16) + (2*w + (TI))) * 8) * 64 + lane; \
    NM##_0 = p[0];   NM##_1 = p[64];  NM##_2 = p[128]; NM##_3 = p[192]; \
    NM##_4 = p[256]; NM##_5 = p[320]; NM##_6 = p[384]; NM##_7 = p[448]; }
  DECLW(wU0, 0, 0) DECLW(wU1, 0, 1)
  DECLW(wR0, 1, 0) DECLW(wR1, 1, 1)
  DECLW(wC0, 2, 0) DECLW(wC1, 2, 1)
#undef DECLW

  const int u0 = (2 * w) * 16 + quad * 4;   // tile 0 unit base for this lane
  const int u1 = u0 + 16;                   // tile 1

  f4v cv0 = *(const f4v*)(c_in + (size_t)(m0 + n) * U_DIM + u0);
  f4v cv1 = *(const f4v*)(c_in + (size_t)(m0 + n) * U_DIM + u1);

  _Float16* cp0 = (_Float16*)ct + ((u0 >> 3) * 16 + n) * 8 + (u0 & 7);
  _Float16* cp1 = (_Float16*)ct + ((u1 >> 3) * 16 + n) * 8 + (u1 & 7);
  _Float16* gp0 = (_Float16*)gt + ((u0 >> 3) * 16 + n) * 8 + (u0 & 7);
  _Float16* gp1 = (_Float16*)gt + ((u1 >> 3) * 16 + n) * 8 + (u1 & 7);

  { h4 t0 = {(_Float16)cv0[0], (_Float16)cv0[1], (_Float16)cv0[2], (_Float16)cv0[3]};
    h4 t1 = {(_Float16)cv1[0], (_Float16)cv1[1], (_Float16)cv1[2], (_Float16)cv1[3]};
    *(h4*)cp0 = t0; *(h4*)cp1 = t1; }

  const size_t rowoff = (size_t)(m0 + n) * len * U_DIM;
  const _Float16* xu0p = XU + rowoff + u0;
  const _Float16* xu1p = XU + rowoff + u1;
  const _Float16* xr0p = XR + rowoff + u0;
  const _Float16* xr1p = XR + rowoff + u1;
  const _Float16* xc0p = XC + rowoff + u0;
  const _Float16* xc1p = XC + rowoff + u1;

  h4 xu0 = *(const h4*)xu0p, xu1 = *(const h4*)xu1p;
  h4 xr0 = *(const h4*)xr0p, xr1 = *(const h4*)xr1p;
  h4 xc0 = *(const h4*)xc0p, xc1 = *(const h4*)xc1p;

  __syncthreads();

  for (int t = 0; t < len; ++t) {
    size_t noff = (size_t)((t + 1 < len) ? t + 1 : t) * U_DIM;
    h4 nxu0 = *(const h4*)(xu0p + noff), nxu1 = *(const h4*)(xu1p + noff);
    h4 nxr0 = *(const h4*)(xr0p + noff), nxr1 = *(const h4*)(xr1p + noff);
    h4 nxc0 = *(const h4*)(xc0p + noff), nxc1 = *(const h4*)(xc1p + noff);

    // phase 1: U and R pre-activations; one B-frag read feeds 4 MFMAs
    f4v aU0 = {0.f,0.f,0.f,0.f}, aU1 = {0.f,0.f,0.f,0.f};
    f4v aR0 = {0.f,0.f,0.f,0.f}, aR1 = {0.f,0.f,0.f,0.f};
#define P1(K) { h8 bf = ct[((K)*4 + quad)*16 + n]; \
    aU0 = __builtin_amdgcn_mfma_f32_16x16x32_f16(wU0_##K, bf, aU0, 0, 0, 0); \
    aU1 = __builtin_amdgcn_mfma_f32_16x16x32_f16(wU1_##K, bf, aU1, 0, 0, 0); \
    aR0 = __builtin_amdgcn_mfma_f32_16x16x32_f16(wR0_##K, bf, aR0, 0, 0, 0); \
    aR1 = __builtin_amdgcn_mfma_f32_16x16x32_f16(wR1_##K, bf, aR1, 0, 0, 0); }
    P1(0) P1(1) P1(2) P1(3) P1(4) P1(5) P1(6) P1(7)
#undef P1

    f4v gu0, gu1;
    h4 g0, g1;
#pragma unroll
    for (int r = 0; r < 4; ++r) {
      gu0[r] = fast_sigmoid(aU0[r] + (float)xu0[r]);
      gu1[r] = fast_sigmoid(aU1[r] + (float)xu1[r]);
      float gr0 = fast_sigmoid(aR0[r] + (float)xr0[r]);
      float gr1 = fast_sigmoid(aR1[r] + (float)xr1[r]);
      g0[r] = (_Float16)(gr0 * cv0[r]);
      g1[r] = (_Float16)(gr1 * cv1[r]);
    }
    *(h4*)gp0 = g0;
    *(h4*)gp1 = g1;
    __syncthreads();

    // phase 2: candidate pre-activation over (g_r * c)
    f4v aC0 = {0.f,0.f,0.f,0.f}, aC1 = {0.f,0.f,0.f,0.f};
#define P2(K) { h8 bf = gt[((K)*4 + quad)*16 + n]; \
    aC0 = __builtin_amdgcn_mfma_f32_16x16x32_f16(wC0_##K, bf, aC0, 0, 0, 0); \
    aC1 = __builtin_amdgcn_mfma_f32_16x16x32_f16(wC1_##K, bf, aC1, 0, 0, 0); }
    P2(0) P2(1) P2(2) P2(3) P2(4) P2(5) P2(6) P2(7)
#undef P2

    h4 c0h, c1h;
#pragma unroll
    for (int r = 0; r < 4; ++r) {
      float cand0 = fast_tanh(aC0[r] + (float)xc0[r]);
      float cand1 = fast_tanh(aC1[r] + (float)xc1[r]);
      cv0[r] = fmaf(gu0[r], cand0 - cv0[r], cv0[r]);
      cv1[r] = fmaf(gu1[r], cand1 - cv1[r], cv1[r]);
      c0h[r] = (_Float16)cv0[r];
      c1h[r] = (_Float16)cv1[r];
    }
    *(h4*)cp0 = c0h;
    *(h4*)cp1 = c1h;

    xu0 = nxu0; xu1 = nxu1; xr0 = nxr0; xr1 = nxr1; xc0 = nxc0; xc1 = nxc1;
    __syncthreads();
  }

  *(f4v*)(c_out + (size_t)(m0 + n) * U_DIM + u0) = cv0;
  *(f4v*)(c_out + (size_t)(m0 + n) * U_DIM + u1) = cv1;
}

// ---------------- host ------------------------------------------------------
extern "C" void kernel_launch(void* const* d_in, const int* in_sizes, int n_in,
                              void* d_out, int out_size, void* d_ws, size_t ws_size,
                              hipStream_t stream) {
  const float* x   = (const float*)d_in[0];
  const float* a0  = (const float*)d_in[1];
  const float* wcx = (const float*)d_in[2];
  const float* wcc = (const float*)d_in[3];
  const float* bc  = (const float*)d_in[4];
  const float* wux = (const float*)d_in[5];
  const float* wuc = (const float*)d_in[6];
  const float* bu  = (const float*)d_in[7];
  const float* wrx = (const float*)d_in[8];
  const float* wrc = (const float*)d_in[9];
  const float* br  = (const float*)d_in[10];
  float* out = (float*)d_out;

  const size_t x16_bytes = (size_t)M_DIM * T_DIM * U_DIM * 2;  // 67.1 MB
  const size_t wt_bytes  = 3ull * 256 * 32 * 16;               // 384 KB
  const size_t wa_bytes  = 3ull * 16 * 8 * 64 * 16;            // 384 KB
  const size_t fixed = x16_bytes + wt_bytes + wa_bytes;

  h8* x16  = (h8*)d_ws;
  h8* wt16 = (h8*)((char*)d_ws + x16_bytes);
  h8* wa   = (h8*)((char*)d_ws + x16_bytes + wt_bytes);
  _Float16* XU0 = (_Float16*)((char*)d_ws + fixed);

  size_t avail = (ws_size > fixed) ? (ws_size - fixed) : 0;
  const size_t perT = 3ull * M_DIM * U_DIM * 2;                // 393 KB / step (fp16)
  int Tc = (int)(avail / perT);
  if (Tc > T_DIM) Tc = T_DIM;
  if (Tc < 1) Tc = 1;
  int nch = (T_DIM + Tc - 1) / Tc;
  Tc = (T_DIM + nch - 1) / nch;

  _Float16* XU = XU0;
  _Float16* XR = XU + (size_t)M_DIM * Tc * U_DIM;
  _Float16* XC = XR + (size_t)M_DIM * Tc * U_DIM;

  conv_x<<<16384, 256, 0, stream>>>(x, x16, M_DIM * T_DIM * U_DIM / 8);
  prep_xw<<<96, 256, 0, stream>>>(wux, wrx, wcx, wt16);
  prep_wa<<<96, 256, 0, stream>>>(wuc, wrc, wcc, wa);

  for (int t0 = 0; t0 < T_DIM; t0 += Tc) {
    int lenc = (T_DIM - t0) < Tc ? (T_DIM - t0) : Tc;
    dim3 g((M_DIM * lenc) / 128, 2, 3);
    xproj_mfma<<<g, 256, 0, stream>>>(x16, wt16, bu, br, bc,
                                      XU, XR, XC, t0, lenc);
    gru_mfma<<<16, 512, 0, stream>>>(XU, XR, XC, wa,
                                     (t0 == 0 ? a0 : out), out, lenc);
  }
}

// Round 6
// 1279.304 us; speedup vs baseline: 1.1837x; 1.1837x over previous
//
#include <hip/hip_runtime.h>

typedef _Float16 h2 __attribute__((ext_vector_type(2)));
typedef _Float16 h4 __attribute__((ext_vector_type(4)));
typedef _Float16 h8 __attribute__((ext_vector_type(8)));
typedef float f4v __attribute__((ext_vector_type(4)));

#define U_DIM 256
#define M_DIM 256
#define T_DIM 512

#if defined(__has_builtin)
#if __has_builtin(__builtin_amdgcn_fdot2)
#define HAVE_FDOT2 1
#endif
#endif

__device__ __forceinline__ float fdot2f(h2 a, h2 b, float c) {
#ifdef HAVE_FDOT2
  return __builtin_amdgcn_fdot2(a, b, c, false);
#else
  return fmaf((float)a[0], (float)b[0], fmaf((float)a[1], (float)b[1], c));
#endif
}

__device__ __forceinline__ float fast_sigmoid(float z) {
  return __builtin_amdgcn_rcpf(1.f + __expf(-z));
}
__device__ __forceinline__ float fast_tanh(float z) {
  return fmaf(2.f, __builtin_amdgcn_rcpf(1.f + __expf(-2.f * z)), -1.f);
}
__device__ __forceinline__ float red8(float v) {  // sum across sp=lane&7
  v += __shfl_xor(v, 1);
  v += __shfl_xor(v, 2);
  v += __shfl_xor(v, 4);
  return v;
}

// ---------------- prep: x fp32 -> fp16 (same [M][T][256] layout) ------------
__global__ void conv_x(const float* __restrict__ x, h8* __restrict__ x16, int n8) {
  int i = blockIdx.x * 256 + threadIdx.x;
  if (i >= n8) return;
  const float4* p = (const float4*)(x + (size_t)i * 8);
  float4 v0 = p[0], v1 = p[1];
  h8 o = {(_Float16)v0.x, (_Float16)v0.y, (_Float16)v0.z, (_Float16)v0.w,
          (_Float16)v1.x, (_Float16)v1.y, (_Float16)v1.z, (_Float16)v1.w};
  x16[i] = o;
}

// ------- prep: x-projection weights -> fp16 TRANSPOSED [mtx][n][k] ----------
__global__ void prep_xw(const float* __restrict__ wux, const float* __restrict__ wrx,
                        const float* __restrict__ wcx, h8* __restrict__ wt16) {
  int idx = blockIdx.x * 256 + threadIdx.x;   // 0..24575
  int mtx = idx >> 13;
  int rem = idx & 8191;
  int n = rem >> 5;
  int kv = rem & 31;
  const float* W = (mtx == 0) ? wux : ((mtx == 1) ? wrx : wcx);
  h8 o;
#pragma unroll
  for (int e = 0; e < 8; ++e) o[e] = (_Float16)W[(size_t)(kv * 8 + e) * U_DIM + n];
  wt16[idx] = o;
}

// ------- prep: recurrent weights for u=4/split=8 scalar-dot -----------------
// thread tid = g*8+sp owns units [4g,4g+4), k-slice [32sp, 32sp+32).
// w48[slot*512 + tid][e] = W[32sp + 8cc + e][4g+uu],  slot = (mtx*4+uu)*4+cc
__global__ void prep_w48(const float* __restrict__ wuc, const float* __restrict__ wrc,
                         const float* __restrict__ wcc, h8* __restrict__ w48) {
  int idx = blockIdx.x * 256 + threadIdx.x;   // 0..24575 (48*512)
  int slot = idx >> 9;
  int tid = idx & 511;
  int mtx = slot >> 4;
  int uu = (slot >> 2) & 3;
  int cc = slot & 3;
  int g = tid >> 3, sp = tid & 7;
  const float* W = (mtx == 0) ? wuc : ((mtx == 1) ? wrc : wcc);
  int j = 4 * g + uu;
  int k0 = 32 * sp + 8 * cc;
  h8 o;
#pragma unroll
  for (int e = 0; e < 8; ++e) o[e] = (_Float16)W[(size_t)(k0 + e) * U_DIM + j];
  w48[idx] = o;
}

// ---------------- xproj via fp16 MFMA, fp16 OUTPUT (unchanged r5) -----------
__global__ __launch_bounds__(256, 2)
void xproj_mfma(const h8* __restrict__ x16, const h8* __restrict__ wt16,
                const float* __restrict__ Bu, const float* __restrict__ Br,
                const float* __restrict__ Bc,
                _Float16* __restrict__ XU, _Float16* __restrict__ XR,
                _Float16* __restrict__ XC, int t0, int len) {
  const int mtx = blockIdx.z;
  const float* Bv = (mtx == 0) ? Bu : ((mtx == 1) ? Br : Bc);
  _Float16* O = (mtx == 0) ? XU : ((mtx == 1) ? XR : XC);
  const h8* W = wt16 + (size_t)mtx * 256 * 32;

  __shared__ _Float16 a_sh[128][40];
  __shared__ _Float16 b_sh[128][40];

  const int tid = threadIdx.x;
  const int r0 = blockIdx.x * 128;
  const int c0 = blockIdx.y * 128;

  const int srow = tid >> 1;
  const int spart = tid & 1;
  const int r = r0 + srow;
  const int mm = r / len;
  const int tc = r - mm * len;
  const h8* arow = x16 + ((size_t)mm * T_DIM + (size_t)(t0 + tc)) * 32;
  const h8* brow = W + (size_t)(c0 + srow) * 32;

  const int lane = tid & 63;
  const int w = tid >> 6;
  const int quad = lane >> 4;
  const int mrow = lane & 15;

  f4v acc[2][8];
#pragma unroll
  for (int fr = 0; fr < 2; ++fr)
#pragma unroll
    for (int fc = 0; fc < 8; ++fc) acc[fr][fc] = f4v{0.f, 0.f, 0.f, 0.f};

  for (int k8 = 0; k8 < 32; k8 += 4) {
    h8 a0 = arow[k8 + 2 * spart];
    h8 a1 = arow[k8 + 2 * spart + 1];
    h8 b0 = brow[k8 + 2 * spart];
    h8 b1 = brow[k8 + 2 * spart + 1];
    __syncthreads();
    *(h8*)&a_sh[srow][spart * 16]     = a0;
    *(h8*)&a_sh[srow][spart * 16 + 8] = a1;
    *(h8*)&b_sh[srow][spart * 16]     = b0;
    *(h8*)&b_sh[srow][spart * 16 + 8] = b1;
    __syncthreads();
    h8 af0 = *(const h8*)&a_sh[32 * w + mrow][quad * 8];
    h8 af1 = *(const h8*)&a_sh[32 * w + 16 + mrow][quad * 8];
#pragma unroll
    for (int fc = 0; fc < 8; ++fc) {
      h8 bf = *(const h8*)&b_sh[fc * 16 + mrow][quad * 8];
      acc[0][fc] = __builtin_amdgcn_mfma_f32_16x16x32_f16(af0, bf, acc[0][fc], 0, 0, 0);
      acc[1][fc] = __builtin_amdgcn_mfma_f32_16x16x32_f16(af1, bf, acc[1][fc], 0, 0, 0);
    }
  }

#pragma unroll
  for (int fc = 0; fc < 8; ++fc) {
    int col = c0 + fc * 16 + mrow;
    float bb = Bv[col];
#pragma unroll
    for (int fr = 0; fr < 2; ++fr)
#pragma unroll
      for (int reg = 0; reg < 4; ++reg) {
        int rr = r0 + 32 * w + fr * 16 + quad * 4 + reg;
        O[(size_t)rr * U_DIM + col] = (_Float16)(acc[fr][fc][reg] + bb);
      }
  }
}

// ---------------- recurrence: u=4 / split=8, 512 thr, 256 blocks ------------
// tid = g*8+sp: units [4g,4g+4), k-slice [32sp,32sp+32).  DS reads/CU-step:
// 64 b128 (r4 had 256).  LDS chunk c stored at padded index c+(c>>2) so the
// 8 sp-groups of a wave read 8 DISJOINT bank-quads (20*sp mod 32 distinct).
__global__ __launch_bounds__(512, 2)
void gru_rec(const _Float16* __restrict__ XU, const _Float16* __restrict__ XR,
             const _Float16* __restrict__ XC, const h8* __restrict__ w48,
             const float* __restrict__ c_in, float* __restrict__ c_out, int len) {
  const int m = blockIdx.x;
  const int tid = threadIdx.x;
  const int g = tid >> 3;
  const int sp = tid & 7;
  const bool sp0 = (sp == 0);

  __shared__ h8 ct[40];  // padded: chunk c at index c + (c>>2)
  __shared__ h8 gt[40];

#define DECLW3(uu, cc) \
  h8 wU##uu##cc = w48[(size_t)((0 * 4 + uu) * 4 + cc) * 512 + tid]; \
  h8 wR##uu##cc = w48[(size_t)((1 * 4 + uu) * 4 + cc) * 512 + tid]; \
  h8 wC##uu##cc = w48[(size_t)((2 * 4 + uu) * 4 + cc) * 512 + tid];
  DECLW3(0, 0) DECLW3(0, 1) DECLW3(0, 2) DECLW3(0, 3)
  DECLW3(1, 0) DECLW3(1, 1) DECLW3(1, 2) DECLW3(1, 3)
  DECLW3(2, 0) DECLW3(2, 1) DECLW3(2, 2) DECLW3(2, 3)
  DECLW3(3, 0) DECLW3(3, 1) DECLW3(3, 2) DECLW3(3, 3)
#undef DECLW3

  // state write slot for units [4g,4g+4): chunk c0=g>>1, half (g&1)
  const int pc0 = (g >> 1) + (g >> 3);            // padded chunk index
  _Float16* cslot = (_Float16*)ct + pc0 * 8 + (g & 1) * 4;
  _Float16* gslot = (_Float16*)gt + pc0 * 8 + (g & 1) * 4;

  f4v cj = *(const f4v*)(c_in + (size_t)m * U_DIM + 4 * g);
  if (sp0) {
    h4 c0h = {(_Float16)cj[0], (_Float16)cj[1], (_Float16)cj[2], (_Float16)cj[3]};
    *(h4*)cslot = c0h;
  }

  const size_t rowbase = (size_t)m * len * U_DIM + 4 * g;
  const _Float16* xup = XU + rowbase;
  const _Float16* xrp = XR + rowbase;
  const _Float16* xcp = XC + rowbase;

  h4 xu = *(const h4*)xup, xr = *(const h4*)xrp, xc = *(const h4*)xcp;

  __syncthreads();

  for (int t = 0; t < len; ++t) {
    size_t noff = (size_t)((t + 1 < len) ? t + 1 : t) * U_DIM;
    h4 nxu = *(const h4*)(xup + noff);
    h4 nxr = *(const h4*)(xrp + noff);
    h4 nxc = *(const h4*)(xcp + noff);

#define D8(acc, wv, cv) \
    acc = fdot2f(h2{cv[0], cv[1]}, h2{wv[0], wv[1]}, acc); \
    acc = fdot2f(h2{cv[2], cv[3]}, h2{wv[2], wv[3]}, acc); \
    acc = fdot2f(h2{cv[4], cv[5]}, h2{wv[4], wv[5]}, acc); \
    acc = fdot2f(h2{cv[6], cv[7]}, h2{wv[6], wv[7]}, acc);

    // ---- pass 1: U and R pre-activations over this thread's k-slice ----
    float pu0 = 0.f, pu1 = 0.f, pu2 = 0.f, pu3 = 0.f;
    float pr0 = 0.f, pr1 = 0.f, pr2 = 0.f, pr3 = 0.f;
#define P1C(cc) { h8 cv = ct[5 * sp + cc]; \
    D8(pu0, wU0##cc, cv) D8(pr0, wR0##cc, cv) \
    D8(pu1, wU1##cc, cv) D8(pr1, wR1##cc, cv) \
    D8(pu2, wU2##cc, cv) D8(pr2, wR2##cc, cv) \
    D8(pu3, wU3##cc, cv) D8(pr3, wR3##cc, cv) }
    P1C(0) P1C(1) P1C(2) P1C(3)
#undef P1C

    pu0 = red8(pu0); pu1 = red8(pu1); pu2 = red8(pu2); pu3 = red8(pu3);
    pr0 = red8(pr0); pr1 = red8(pr1); pr2 = red8(pr2); pr3 = red8(pr3);

    f4v gu;
    if (sp0) {
      gu[0] = fast_sigmoid(pu0 + (float)xu[0]);
      gu[1] = fast_sigmoid(pu1 + (float)xu[1]);
      gu[2] = fast_sigmoid(pu2 + (float)xu[2]);
      gu[3] = fast_sigmoid(pu3 + (float)xu[3]);
      float gr0 = fast_sigmoid(pr0 + (float)xr[0]);
      float gr1 = fast_sigmoid(pr1 + (float)xr[1]);
      float gr2 = fast_sigmoid(pr2 + (float)xr[2]);
      float gr3 = fast_sigmoid(pr3 + (float)xr[3]);
      h4 gh = {(_Float16)(gr0 * cj[0]), (_Float16)(gr1 * cj[1]),
               (_Float16)(gr2 * cj[2]), (_Float16)(gr3 * cj[3])};
      *(h4*)gslot = gh;
    }
    __syncthreads();

    // ---- pass 2: candidate pre-activation over (g_r * c) ----
    float pc0 = 0.f, pc1 = 0.f, pc2 = 0.f, pc3 = 0.f;
#define P2C(cc) { h8 hv = gt[5 * sp + cc]; \
    D8(pc0, wC0##cc, hv) D8(pc1, wC1##cc, hv) \
    D8(pc2, wC2##cc, hv) D8(pc3, wC3##cc, hv) }
    P2C(0) P2C(1) P2C(2) P2C(3)
#undef P2C
#undef D8

    pc0 = red8(pc0); pc1 = red8(pc1); pc2 = red8(pc2); pc3 = red8(pc3);

    if (sp0) {
      float cand0 = fast_tanh(pc0 + (float)xc[0]);
      float cand1 = fast_tanh(pc1 + (float)xc[1]);
      float cand2 = fast_tanh(pc2 + (float)xc[2]);
      float cand3 = fast_tanh(pc3 + (float)xc[3]);
      cj[0] = fmaf(gu[0], cand0 - cj[0], cj[0]);
      cj[1] = fmaf(gu[1], cand1 - cj[1], cj[1]);
      cj[2] = fmaf(gu[2], cand2 - cj[2], cj[2]);
      cj[3] = fmaf(gu[3], cand3 - cj[3], cj[3]);
      h4 ch = {(_Float16)cj[0], (_Float16)cj[1], (_Float16)cj[2], (_Float16)cj[3]};
      *(h4*)cslot = ch;
    }

    xu = nxu; xr = nxr; xc = nxc;
    __syncthreads();
  }

  if (sp0) *(f4v*)(c_out + (size_t)m * U_DIM + 4 * g) = cj;
}

// ---------------- host ------------------------------------------------------
extern "C" void kernel_launch(void* const* d_in, const int* in_sizes, int n_in,
                              void* d_out, int out_size, void* d_ws, size_t ws_size,
                              hipStream_t stream) {
  const float* x   = (const float*)d_in[0];
  const float* a0  = (const float*)d_in[1];
  const float* wcx = (const float*)d_in[2];
  const float* wcc = (const float*)d_in[3];
  const float* bc  = (const float*)d_in[4];
  const float* wux = (const float*)d_in[5];
  const float* wuc = (const float*)d_in[6];
  const float* bu  = (const float*)d_in[7];
  const float* wrx = (const float*)d_in[8];
  const float* wrc = (const float*)d_in[9];
  const float* br  = (const float*)d_in[10];
  float* out = (float*)d_out;

  const size_t x16_bytes = (size_t)M_DIM * T_DIM * U_DIM * 2;  // 67.1 MB
  const size_t wt_bytes  = 3ull * 256 * 32 * 16;               // 384 KB
  const size_t w48_bytes = 48ull * 512 * 16;                   // 384 KB
  const size_t fixed = x16_bytes + wt_bytes + w48_bytes;

  h8* x16  = (h8*)d_ws;
  h8* wt16 = (h8*)((char*)d_ws + x16_bytes);
  h8* w48  = (h8*)((char*)d_ws + x16_bytes + wt_bytes);
  _Float16* XU0 = (_Float16*)((char*)d_ws + fixed);

  size_t avail = (ws_size > fixed) ? (ws_size - fixed) : 0;
  const size_t perT = 3ull * M_DIM * U_DIM * 2;                // 393 KB / step
  int Tc = (int)(avail / perT);
  if (Tc > T_DIM) Tc = T_DIM;
  if (Tc < 1) Tc = 1;
  int nch = (T_DIM + Tc - 1) / Tc;
  Tc = (T_DIM + nch - 1) / nch;

  _Float16* XU = XU0;
  _Float16* XR = XU + (size_t)M_DIM * Tc * U_DIM;
  _Float16* XC = XR + (size_t)M_DIM * Tc * U_DIM;

  conv_x<<<16384, 256, 0, stream>>>(x, x16, M_DIM * T_DIM * U_DIM / 8);
  prep_xw<<<96, 256, 0, stream>>>(wux, wrx, wcx, wt16);
  prep_w48<<<96, 256, 0, stream>>>(wuc, wrc, wcc, w48);

  for (int t0 = 0; t0 < T_DIM; t0 += Tc) {
    int lenc = (T_DIM - t0) < Tc ? (T_DIM - t0) : Tc;
    dim3 g((M_DIM * lenc) / 128, 2, 3);
    xproj_mfma<<<g, 256, 0, stream>>>(x16, wt16, bu, br, bc,
                                      XU, XR, XC, t0, lenc);
    gru_rec<<<M_DIM, 512, 0, stream>>>(XU, XR, XC, w48,
                                       (t0 == 0 ? a0 : out), out, lenc);
  }
}

// Round 7
// 972.658 us; speedup vs baseline: 1.5569x; 1.3153x over previous
//
#include <hip/hip_runtime.h>

typedef _Float16 h2 __attribute__((ext_vector_type(2)));
typedef _Float16 h4 __attribute__((ext_vector_type(4)));
typedef _Float16 h8 __attribute__((ext_vector_type(8)));
typedef float f4v __attribute__((ext_vector_type(4)));

#define U_DIM 256
#define M_DIM 256
#define T_DIM 512

#if defined(__has_builtin)
#if __has_builtin(__builtin_amdgcn_fdot2)
#define HAVE_FDOT2 1
#endif
#endif

__device__ __forceinline__ float fdot2f(h2 a, h2 b, float c) {
#ifdef HAVE_FDOT2
  return __builtin_amdgcn_fdot2(a, b, c, false);
#else
  return fmaf((float)a[0], (float)b[0], fmaf((float)a[1], (float)b[1], c));
#endif
}

__device__ __forceinline__ float fast_sigmoid(float z) {
  return __builtin_amdgcn_rcpf(1.f + __expf(-z));
}
__device__ __forceinline__ float fast_tanh(float z) {
  return fmaf(2.f, __builtin_amdgcn_rcpf(1.f + __expf(-2.f * z)), -1.f);
}

// ---------------- prep: x fp32 -> fp16 (same [M][T][256] layout) ------------
__global__ void conv_x(const float* __restrict__ x, h8* __restrict__ x16, int n8) {
  int i = blockIdx.x * 256 + threadIdx.x;
  if (i >= n8) return;
  const float4* p = (const float4*)(x + (size_t)i * 8);
  float4 v0 = p[0], v1 = p[1];
  h8 o = {(_Float16)v0.x, (_Float16)v0.y, (_Float16)v0.z, (_Float16)v0.w,
          (_Float16)v1.x, (_Float16)v1.y, (_Float16)v1.z, (_Float16)v1.w};
  x16[i] = o;
}

// ------- prep: x-projection weights -> fp16 TRANSPOSED [mtx][n][k] ----------
__global__ void prep_xw(const float* __restrict__ wux, const float* __restrict__ wrx,
                        const float* __restrict__ wcx, h8* __restrict__ wt16) {
  int idx = blockIdx.x * 256 + threadIdx.x;   // 0..24575
  int mtx = idx >> 13;
  int rem = idx & 8191;
  int n = rem >> 5;
  int kv = rem & 31;
  const float* W = (mtx == 0) ? wux : ((mtx == 1) ? wrx : wcx);
  h8 o;
#pragma unroll
  for (int e = 0; e < 8; ++e) o[e] = (_Float16)W[(size_t)(kv * 8 + e) * U_DIM + n];
  wt16[idx] = o;
}

// ---------------- prep: recurrent weights fp16, [mtx][tid][v] (r4 layout) ---
// tid = 2j+s; w16[(mtx*512+tid)*16+v][e] = W[128s + 8v + e][j]
__global__ void prep_w(const float* __restrict__ wuc, const float* __restrict__ wrc,
                       const float* __restrict__ wcc, h8* __restrict__ w16) {
  int idx = blockIdx.x * 256 + threadIdx.x;   // 0..24575
  int mtx = idx >> 13;
  int rem = idx & 8191;
  int tid = rem >> 4;
  int v   = rem & 15;
  int j = tid >> 1, s = tid & 1;
  const float* W = (mtx == 0) ? wuc : ((mtx == 1) ? wrc : wcc);
  int k0 = 128 * s + 8 * v;
  h8 o;
#pragma unroll
  for (int e = 0; e < 8; ++e) o[e] = (_Float16)W[(size_t)(k0 + e) * U_DIM + j];
  w16[idx] = o;
}

// ---------------- xproj via fp16 MFMA, fp16 OUTPUT (r5, unchanged) ----------
__global__ __launch_bounds__(256, 2)
void xproj_mfma(const h8* __restrict__ x16, const h8* __restrict__ wt16,
                const float* __restrict__ Bu, const float* __restrict__ Br,
                const float* __restrict__ Bc,
                _Float16* __restrict__ XU, _Float16* __restrict__ XR,
                _Float16* __restrict__ XC, int t0, int len) {
  const int mtx = blockIdx.z;
  const float* Bv = (mtx == 0) ? Bu : ((mtx == 1) ? Br : Bc);
  _Float16* O = (mtx == 0) ? XU : ((mtx == 1) ? XR : XC);
  const h8* W = wt16 + (size_t)mtx * 256 * 32;

  __shared__ _Float16 a_sh[128][40];
  __shared__ _Float16 b_sh[128][40];

  const int tid = threadIdx.x;
  const int r0 = blockIdx.x * 128;
  const int c0 = blockIdx.y * 128;

  const int srow = tid >> 1;
  const int spart = tid & 1;
  const int r = r0 + srow;
  const int mm = r / len;
  const int tc = r - mm * len;
  const h8* arow = x16 + ((size_t)mm * T_DIM + (size_t)(t0 + tc)) * 32;
  const h8* brow = W + (size_t)(c0 + srow) * 32;

  const int lane = tid & 63;
  const int w = tid >> 6;
  const int quad = lane >> 4;
  const int mrow = lane & 15;

  f4v acc[2][8];
#pragma unroll
  for (int fr = 0; fr < 2; ++fr)
#pragma unroll
    for (int fc = 0; fc < 8; ++fc) acc[fr][fc] = f4v{0.f, 0.f, 0.f, 0.f};

  for (int k8 = 0; k8 < 32; k8 += 4) {
    h8 a0 = arow[k8 + 2 * spart];
    h8 a1 = arow[k8 + 2 * spart + 1];
    h8 b0 = brow[k8 + 2 * spart];
    h8 b1 = brow[k8 + 2 * spart + 1];
    __syncthreads();
    *(h8*)&a_sh[srow][spart * 16]     = a0;
    *(h8*)&a_sh[srow][spart * 16 + 8] = a1;
    *(h8*)&b_sh[srow][spart * 16]     = b0;
    *(h8*)&b_sh[srow][spart * 16 + 8] = b1;
    __syncthreads();
    h8 af0 = *(const h8*)&a_sh[32 * w + mrow][quad * 8];
    h8 af1 = *(const h8*)&a_sh[32 * w + 16 + mrow][quad * 8];
#pragma unroll
    for (int fc = 0; fc < 8; ++fc) {
      h8 bf = *(const h8*)&b_sh[fc * 16 + mrow][quad * 8];
      acc[0][fc] = __builtin_amdgcn_mfma_f32_16x16x32_f16(af0, bf, acc[0][fc], 0, 0, 0);
      acc[1][fc] = __builtin_amdgcn_mfma_f32_16x16x32_f16(af1, bf, acc[1][fc], 0, 0, 0);
    }
  }

#pragma unroll
  for (int fc = 0; fc < 8; ++fc) {
    int col = c0 + fc * 16 + mrow;
    float bb = Bv[col];
#pragma unroll
    for (int fr = 0; fr < 2; ++fr)
#pragma unroll
      for (int reg = 0; reg < 4; ++reg) {
        int rr = r0 + 32 * w + fr * 16 + quad * 4 + reg;
        O[(size_t)rr * U_DIM + col] = (_Float16)(acc[fr][fc][reg] + bb);
      }
  }
}

// ---------------- recurrence: r4-measured-best structure, fp16 gates --------
// 512 thr/block, tid=2j+s, thread owns k-slice [128s,128s+128) in 48 named h8
// (192 regs, register/AGPR-resident -- FETCH flat at ~100MB is the no-spill
// tripwire).  LDS chunk pad (cb=s*17) keeps the two broadcast groups on
// disjoint banks (r4: conflicts 1.3e8 -> 0).  Only delta vs r4: gate arrays
// are fp16 (halves GEMM-output + gate-load traffic).
__global__ __launch_bounds__(512, 2)
void gru_rec(const _Float16* __restrict__ XU, const _Float16* __restrict__ XR,
             const _Float16* __restrict__ XC, const h8* __restrict__ w16,
             const float* __restrict__ c_in, float* __restrict__ c_out, int len) {
  const int m = blockIdx.x;
  const int tid = threadIdx.x;
  const int j = tid >> 1;
  const int s = tid & 1;
  const int cb = s * 17;                    // padded chunk base
  const int wj = j + ((j >> 7) << 3);       // padded elem index for writes

  __shared__ h8 ch8[34];
  __shared__ h8 hh8[34];

  const h8* wub = w16 + (size_t)tid * 16;
  const h8* wrb = wub + 8192;
  const h8* wcb = wub + 16384;

#define DECL_W(i) h8 wu##i = wub[i]; h8 wr##i = wrb[i]; h8 wc##i = wcb[i];
  DECL_W(0)  DECL_W(1)  DECL_W(2)  DECL_W(3)
  DECL_W(4)  DECL_W(5)  DECL_W(6)  DECL_W(7)
  DECL_W(8)  DECL_W(9)  DECL_W(10) DECL_W(11)
  DECL_W(12) DECL_W(13) DECL_W(14) DECL_W(15)
#undef DECL_W

  float cj = c_in[m * U_DIM + j];
  if (s == 0) ((_Float16*)ch8)[wj] = (_Float16)cj;

  const _Float16* XUb = XU + (size_t)m * len * U_DIM;
  const _Float16* XRb = XR + (size_t)m * len * U_DIM;
  const _Float16* XCb = XC + (size_t)m * len * U_DIM;

  int off = j;
  float xuv = (float)XUb[off], xrv = (float)XRb[off], xcv = (float)XCb[off];

  __syncthreads();

  for (int t = 0; t < len; ++t) {
    int offn = off + ((t + 1 < len) ? U_DIM : 0);
    float nxu = (float)XUb[offn], nxr = (float)XRb[offn], nxc = (float)XCb[offn];

    float pu0 = 0.f, pu1 = 0.f, pr0 = 0.f, pr1 = 0.f;
#define PASS1(i) { h8 cv = ch8[cb + i];                                   \
    pu0 = fdot2f(h2{cv[0], cv[1]}, h2{wu##i[0], wu##i[1]}, pu0);          \
    pr0 = fdot2f(h2{cv[0], cv[1]}, h2{wr##i[0], wr##i[1]}, pr0);          \
    pu1 = fdot2f(h2{cv[2], cv[3]}, h2{wu##i[2], wu##i[3]}, pu1);          \
    pr1 = fdot2f(h2{cv[2], cv[3]}, h2{wr##i[2], wr##i[3]}, pr1);          \
    pu0 = fdot2f(h2{cv[4], cv[5]}, h2{wu##i[4], wu##i[5]}, pu0);          \
    pr0 = fdot2f(h2{cv[4], cv[5]}, h2{wr##i[4], wr##i[5]}, pr0);          \
    pu1 = fdot2f(h2{cv[6], cv[7]}, h2{wu##i[6], wu##i[7]}, pu1);          \
    pr1 = fdot2f(h2{cv[6], cv[7]}, h2{wr##i[6], wr##i[7]}, pr1); }
    PASS1(0)  PASS1(1)  PASS1(2)  PASS1(3)
    PASS1(4)  PASS1(5)  PASS1(6)  PASS1(7)
    PASS1(8)  PASS1(9)  PASS1(10) PASS1(11)
    PASS1(12) PASS1(13) PASS1(14) PASS1(15)
#undef PASS1

    float pu = pu0 + pu1;
    pu += __shfl_xor(pu, 1);
    float pr = pr0 + pr1;
    pr += __shfl_xor(pr, 1);

    float gu = fast_sigmoid(pu + xuv);
    float gr = fast_sigmoid(pr + xrv);
    if (s == 0) ((_Float16*)hh8)[wj] = (_Float16)(gr * cj);
    __syncthreads();

    float pc0 = 0.f, pc1 = 0.f;
#define PASS2(i) { h8 hv = hh8[cb + i];                                   \
    pc0 = fdot2f(h2{hv[0], hv[1]}, h2{wc##i[0], wc##i[1]}, pc0);          \
    pc1 = fdot2f(h2{hv[2], hv[3]}, h2{wc##i[2], wc##i[3]}, pc1);          \
    pc0 = fdot2f(h2{hv[4], hv[5]}, h2{wc##i[4], wc##i[5]}, pc0);          \
    pc1 = fdot2f(h2{hv[6], hv[7]}, h2{wc##i[6], wc##i[7]}, pc1); }
    PASS2(0)  PASS2(1)  PASS2(2)  PASS2(3)
    PASS2(4)  PASS2(5)  PASS2(6)  PASS2(7)
    PASS2(8)  PASS2(9)  PASS2(10) PASS2(11)
    PASS2(12) PASS2(13) PASS2(14) PASS2(15)
#undef PASS2

    float pc = pc0 + pc1;
    pc += __shfl_xor(pc, 1);

    float cand = fast_tanh(pc + xcv);
    cj = fmaf(gu, cand - cj, cj);
    if (s == 0) ((_Float16*)ch8)[wj] = (_Float16)cj;

    xuv = nxu; xrv = nxr; xcv = nxc; off = offn;
    __syncthreads();
  }

  if (s == 0) c_out[m * U_DIM + j] = cj;
}

// ---------------- host ------------------------------------------------------
extern "C" void kernel_launch(void* const* d_in, const int* in_sizes, int n_in,
                              void* d_out, int out_size, void* d_ws, size_t ws_size,
                              hipStream_t stream) {
  const float* x   = (const float*)d_in[0];
  const float* a0  = (const float*)d_in[1];
  const float* wcx = (const float*)d_in[2];
  const float* wcc = (const float*)d_in[3];
  const float* bc  = (const float*)d_in[4];
  const float* wux = (const float*)d_in[5];
  const float* wuc = (const float*)d_in[6];
  const float* bu  = (const float*)d_in[7];
  const float* wrx = (const float*)d_in[8];
  const float* wrc = (const float*)d_in[9];
  const float* br  = (const float*)d_in[10];
  float* out = (float*)d_out;

  const size_t x16_bytes = (size_t)M_DIM * T_DIM * U_DIM * 2;  // 67.1 MB
  const size_t wt_bytes  = 3ull * 256 * 32 * 16;               // 384 KB
  const size_t w16_bytes = 3ull * 512 * 16 * 16;               // 384 KB
  const size_t fixed = x16_bytes + wt_bytes + w16_bytes;

  h8* x16  = (h8*)d_ws;
  h8* wt16 = (h8*)((char*)d_ws + x16_bytes);
  h8* w16  = (h8*)((char*)d_ws + x16_bytes + wt_bytes);
  _Float16* XU0 = (_Float16*)((char*)d_ws + fixed);

  size_t avail = (ws_size > fixed) ? (ws_size - fixed) : 0;
  const size_t perT = 3ull * M_DIM * U_DIM * 2;                // 393 KB / step
  int Tc = (int)(avail / perT);
  if (Tc > T_DIM) Tc = T_DIM;
  if (Tc < 1) Tc = 1;
  int nch = (T_DIM + Tc - 1) / Tc;
  Tc = (T_DIM + nch - 1) / nch;

  _Float16* XU = XU0;
  _Float16* XR = XU + (size_t)M_DIM * Tc * U_DIM;
  _Float16* XC = XR + (size_t)M_DIM * Tc * U_DIM;

  conv_x<<<16384, 256, 0, stream>>>(x, x16, M_DIM * T_DIM * U_DIM / 8);
  prep_xw<<<96, 256, 0, stream>>>(wux, wrx, wcx, wt16);
  prep_w<<<96, 256, 0, stream>>>(wuc, wrc, wcc, w16);

  for (int t0 = 0; t0 < T_DIM; t0 += Tc) {
    int lenc = (T_DIM - t0) < Tc ? (T_DIM - t0) : Tc;
    dim3 g((M_DIM * lenc) / 128, 2, 3);
    xproj_mfma<<<g, 256, 0, stream>>>(x16, wt16, bu, br, bc,
                                      XU, XR, XC, t0, lenc);
    gru_rec<<<M_DIM, 512, 0, stream>>>(XU, XR, XC, w16,
                                       (t0 == 0 ? a0 : out), out, lenc);
  }
}